// Round 1
// baseline (945.755 us; speedup 1.0000x reference)
//
#include <hip/hip_runtime.h>

#define K_CODES 1024
#define DIM 128
#define TOK_PER_BLK 64
#define ROWSTRIDE 132  // 128 + 4 pad: breaks LDS bank alignment for row reads

// ---------------------------------------------------------------------------
// Kernel 1: codebook squared norms ||e_k||^2 -> cbn[k]
// ---------------------------------------------------------------------------
__global__ __launch_bounds__(64) void vq_cbnorm(const float* __restrict__ cb,
                                                float* __restrict__ cbn) {
    const int c = blockIdx.x;
    const int t = threadIdx.x;
    float v0 = cb[c * DIM + t];
    float v1 = cb[c * DIM + 64 + t];
    float s = v0 * v0 + v1 * v1;
    #pragma unroll
    for (int off = 32; off > 0; off >>= 1) s += __shfl_down(s, off, 64);
    if (t == 0) cbn[c] = s;
}

// ---------------------------------------------------------------------------
// Kernel 2: main VQ. One token per lane, 64 tokens per block (1 wave).
// dist(t,k) = ||e_k||^2 - 2 x_t . e_k   (||x||^2 dropped: constant per row)
// ---------------------------------------------------------------------------
__global__ __launch_bounds__(64) void vq_main(const float* __restrict__ x,
                                              const float* __restrict__ cb,
                                              const float* __restrict__ cbn,
                                              float* __restrict__ xq,
                                              float* __restrict__ loss) {
    __shared__ float lds[TOK_PER_BLK * ROWSTRIDE];
    const int tid = threadIdx.x;
    const long long tileBase = (long long)blockIdx.x * (TOK_PER_BLK * DIM);

    // ---- coalesced global -> LDS stage of this block's 64 token rows ----
    const float4* xg4 = (const float4*)(x + tileBase);
    #pragma unroll
    for (int i = 0; i < 32; ++i) {
        int g = tid + i * 64;              // float4 index within tile [0,2048)
        float4 v = xg4[g];
        int row = g >> 5;                  // 32 float4 per row
        int col = (g & 31) << 2;
        *(float4*)&lds[row * ROWSTRIDE + col] = v;
    }
    __syncthreads();

    // ---- own token row LDS -> registers ----
    float xr[DIM];
    #pragma unroll
    for (int j = 0; j < 32; ++j) {
        float4 v = *(const float4*)&lds[tid * ROWSTRIDE + 4 * j];
        xr[4 * j]     = v.x;
        xr[4 * j + 1] = v.y;
        xr[4 * j + 2] = v.z;
        xr[4 * j + 3] = v.w;
    }

    // ---- argmin over 1024 codes; codebook via wave-uniform (scalar) loads ----
    float best = 3.4e38f;
    int bestk = 0;
    for (int k = 0; k < K_CODES; k += 4) {
        const float* e0 = cb + (size_t)k * DIM;
        float a00 = 0.f, a01 = 0.f, a10 = 0.f, a11 = 0.f;
        float a20 = 0.f, a21 = 0.f, a30 = 0.f, a31 = 0.f;
        #pragma unroll
        for (int d = 0; d < DIM; d += 2) {
            float x0 = xr[d], x1 = xr[d + 1];
            a00 += x0 * e0[d];           a01 += x1 * e0[d + 1];
            a10 += x0 * e0[DIM + d];     a11 += x1 * e0[DIM + d + 1];
            a20 += x0 * e0[2*DIM + d];   a21 += x1 * e0[2*DIM + d + 1];
            a30 += x0 * e0[3*DIM + d];   a31 += x1 * e0[3*DIM + d + 1];
        }
        float d0 = cbn[k]     - 2.f * (a00 + a01);
        float d1 = cbn[k + 1] - 2.f * (a10 + a11);
        float d2 = cbn[k + 2] - 2.f * (a20 + a21);
        float d3 = cbn[k + 3] - 2.f * (a30 + a31);
        // strict < keeps the FIRST minimum (jnp.argmin tie semantics)
        if (d0 < best) { best = d0; bestk = k; }
        if (d1 < best) { best = d1; bestk = k + 1; }
        if (d2 < best) { best = d2; bestk = k + 2; }
        if (d3 < best) { best = d3; bestk = k + 3; }
    }

    // ---- epilogue: gather winning code, recompute diff^2 exactly like ref ----
    const float4* e4 = (const float4*)(cb + (size_t)bestk * DIM);
    float ssum = 0.f;
    #pragma unroll
    for (int j = 0; j < 32; ++j) {
        float4 v = e4[j];
        float d0 = v.x - xr[4 * j];
        float d1 = v.y - xr[4 * j + 1];
        float d2 = v.z - xr[4 * j + 2];
        float d3 = v.w - xr[4 * j + 3];
        ssum += d0 * d0 + d1 * d1 + d2 * d2 + d3 * d3;
        *(float4*)&lds[tid * ROWSTRIDE + 4 * j] = v;   // stage x_q row for transpose
    }
    __syncthreads();

    // ---- coalesced x_q store via LDS transpose (same mapping as the load) ----
    float4* xq4 = (float4*)(xq + tileBase);
    #pragma unroll
    for (int i = 0; i < 32; ++i) {
        int g = tid + i * 64;
        int row = g >> 5;
        int col = (g & 31) << 2;
        xq4[g] = *(const float4*)&lds[row * ROWSTRIDE + col];
    }

    // ---- loss: 1.25 * mean over (n,d) of diff^2, one (b,s) per 2 blocks ----
    #pragma unroll
    for (int off = 32; off > 0; off >>= 1) ssum += __shfl_down(ssum, off, 64);
    if (tid == 0) {
        int bs = blockIdx.x >> 1;   // (block*64 tokens) / 128 = N-dim groups
        atomicAdd(&loss[bs], ssum * (1.25f / 16384.f));  // / (N=128 * D=128)
    }
}

// ---------------------------------------------------------------------------
extern "C" void kernel_launch(void* const* d_in, const int* in_sizes, int n_in,
                              void* d_out, int out_size, void* d_ws, size_t ws_size,
                              hipStream_t stream) {
    const float* x  = (const float*)d_in[0];   // [8,64,128,128] fp32
    const float* cb = (const float*)d_in[1];   // [1024,128] fp32
    float* out  = (float*)d_out;
    float* xq   = out;                          // 8388608 floats
    float* loss = out + (size_t)8 * 64 * 128 * 128;  // 512 floats
    float* cbn  = (float*)d_ws;                 // 1024 floats scratch

    hipMemsetAsync(loss, 0, 512 * sizeof(float), stream);
    vq_cbnorm<<<K_CODES, 64, 0, stream>>>(cb, cbn);
    vq_main<<<1024, 64, 0, stream>>>(x, cb, cbn, xq, loss);
}

// Round 2
// 185.042 us; speedup vs baseline: 5.1110x; 5.1110x over previous
//
#include <hip/hip_runtime.h>

typedef short s16x8 __attribute__((ext_vector_type(8)));
typedef float f32x4 __attribute__((ext_vector_type(4)));

#define MARGIN 0.05f

__device__ inline unsigned short bf16_rn(float f) {
  unsigned int u = __float_as_uint(f);
  return (unsigned short)((u + 0x7FFFu + ((u >> 16) & 1u)) >> 16);
}
__device__ inline float bf16f(unsigned short h) {
  return __uint_as_float(((unsigned int)h) << 16);
}

// ---------------------------------------------------------------------------
// Kernel 1: x (fp32) -> x_hi, x_lo (bf16 as ushort), row-major [T][128]
// ---------------------------------------------------------------------------
__global__ __launch_bounds__(256) void vq_convert_x(const float* __restrict__ x,
                                                    unsigned short* __restrict__ xhi,
                                                    unsigned short* __restrict__ xlo) {
  size_t t = (size_t)blockIdx.x * 256 + threadIdx.x;  // handles 8 floats
  const float* p = x + t * 8;
  float4 a = *(const float4*)p, b = *(const float4*)(p + 4);
  float v[8] = {a.x, a.y, a.z, a.w, b.x, b.y, b.z, b.w};
  unsigned int hw[4], lw[4];
#pragma unroll
  for (int i = 0; i < 4; ++i) {
    unsigned short h0 = bf16_rn(v[2 * i]), h1 = bf16_rn(v[2 * i + 1]);
    float r0 = v[2 * i] - bf16f(h0), r1 = v[2 * i + 1] - bf16f(h1);
    unsigned short l0 = bf16_rn(r0), l1 = bf16_rn(r1);
    hw[i] = (unsigned)h0 | ((unsigned)h1 << 16);
    lw[i] = (unsigned)l0 | ((unsigned)l1 << 16);
  }
  *(uint4*)(xhi + t * 8) = make_uint4(hw[0], hw[1], hw[2], hw[3]);
  *(uint4*)(xlo + t * 8) = make_uint4(lw[0], lw[1], lw[2], lw[3]);
}

// ---------------------------------------------------------------------------
// Kernel 2: codebook -> tiled, XOR-swizzled hi/lo bf16 image + fp32 norms.
// Image: [tile 0..15][ hi: 64 rows x 128 ushort | lo: same ], row r swizzled:
// chunk c (8 dims) stored at chunk position c ^ (r & 15).
// ---------------------------------------------------------------------------
__global__ __launch_bounds__(64) void vq_convert_cb(const float* __restrict__ cb,
                                                    unsigned short* __restrict__ cbimg,
                                                    float* __restrict__ cbn) {
  int k = blockIdx.x * 64 + threadIdx.x;  // code row 0..1023
  int tile = k >> 6, r = k & 63, sm = r & 15;
  const float* row = cb + (size_t)k * 128;
  float nrm = 0.f;
#pragma unroll
  for (int c = 0; c < 16; ++c) {
    float4 a = *(const float4*)(row + c * 8);
    float4 b = *(const float4*)(row + c * 8 + 4);
    float v[8] = {a.x, a.y, a.z, a.w, b.x, b.y, b.z, b.w};
    unsigned int hw[4], lw[4];
#pragma unroll
    for (int i = 0; i < 4; ++i) {
      unsigned short h0 = bf16_rn(v[2 * i]), h1 = bf16_rn(v[2 * i + 1]);
      float r0 = v[2 * i] - bf16f(h0), r1 = v[2 * i + 1] - bf16f(h1);
      unsigned short l0 = bf16_rn(r0), l1 = bf16_rn(r1);
      hw[i] = (unsigned)h0 | ((unsigned)h1 << 16);
      lw[i] = (unsigned)l0 | ((unsigned)l1 << 16);
      nrm += v[2 * i] * v[2 * i] + v[2 * i + 1] * v[2 * i + 1];
    }
    int cs = c ^ sm;
    unsigned short* dh = cbimg + (size_t)tile * 16384 + r * 128 + cs * 8;
    *(uint4*)dh = make_uint4(hw[0], hw[1], hw[2], hw[3]);
    *(uint4*)(dh + 8192) = make_uint4(lw[0], lw[1], lw[2], lw[3]);
  }
  cbn[k] = nrm;
}

// ---------------------------------------------------------------------------
// Kernel 3: main. 256 blocks x 256 thr (4 waves). Wave owns 64 tokens
// (A-frags in regs, hi+lo). Codebook streams via dbuf LDS, 16 tiles x 64
// codes. dist = ||e||^2 - 2 x.e via 3-pass split-bf16 MFMA. Tracks top-2;
// margin cases rescored fp32-exact in epilogue.
// ---------------------------------------------------------------------------
__global__ __launch_bounds__(256) void vq_main(
    const unsigned short* __restrict__ xhi, const unsigned short* __restrict__ xlo,
    const unsigned short* __restrict__ cbimg, const float* __restrict__ cbn,
    const float* __restrict__ cb, const float* __restrict__ xg,
    float* __restrict__ xq, float* __restrict__ loss) {
  __shared__ __attribute__((aligned(16))) unsigned short sB[2][16384];  // 64 KB
  const int tid = threadIdx.x;
  const int wave = tid >> 6, lane = tid & 63;
  const int i0 = lane & 15, q = lane >> 4;
  const int tok0 = blockIdx.x * 256 + wave * 64;

  // ---- A fragments: token row = tok0 + r*16 + i0, dims k = kf*32 + q*8 + j ----
  s16x8 ahi[4][4], alo[4][4];
#pragma unroll
  for (int r = 0; r < 4; ++r)
#pragma unroll
    for (int kf = 0; kf < 4; ++kf) {
      size_t off = (size_t)(tok0 + r * 16 + i0) * 128 + kf * 32 + q * 8;
      ahi[r][kf] = *(const s16x8*)(xhi + off);
      alo[r][kf] = *(const s16x8*)(xlo + off);
    }

  // precomputed LDS byte-offset bases (ushort idx) for B-frag reads
  int boff[4][4];
#pragma unroll
  for (int ks = 0; ks < 4; ++ks)
#pragma unroll
    for (int c = 0; c < 4; ++c)
      boff[ks][c] = (c * 16 + i0) * 128 + (((ks * 4 + q) ^ i0) * 8);

  // stage tile 0
#pragma unroll
  for (int i = 0; i < 8; ++i)
    *(uint4*)&sB[0][i * 2048 + tid * 8] = *(const uint4*)(cbimg + i * 2048 + tid * 8);

  float best[4][4], m2[4][4];
  int bk[4][4], k2[4][4];
#pragma unroll
  for (int r = 0; r < 4; ++r)
#pragma unroll
    for (int g = 0; g < 4; ++g) {
      best[r][g] = 3.4e38f; m2[r][g] = 3.4e38f; bk[r][g] = 0; k2[r][g] = 0;
    }
  __syncthreads();

  for (int t = 0; t < 16; ++t) {
    const int cur = t & 1;
    uint4 pf[8];
    if (t < 15) {
#pragma unroll
      for (int i = 0; i < 8; ++i)
        pf[i] = *(const uint4*)(cbimg + (size_t)(t + 1) * 16384 + i * 2048 + tid * 8);
    }
    f32x4 acc[4][4];
#pragma unroll
    for (int r = 0; r < 4; ++r)
#pragma unroll
      for (int c = 0; c < 4; ++c) acc[r][c] = (f32x4){0.f, 0.f, 0.f, 0.f};

#pragma unroll
    for (int ks = 0; ks < 4; ++ks) {
      s16x8 bhi[4], blo[4];
#pragma unroll
      for (int c = 0; c < 4; ++c) {
        bhi[c] = *(const s16x8*)&sB[cur][boff[ks][c]];
        blo[c] = *(const s16x8*)&sB[cur][boff[ks][c] + 8192];
      }
#pragma unroll
      for (int r = 0; r < 4; ++r)
#pragma unroll
        for (int c = 0; c < 4; ++c) {
          acc[r][c] = __builtin_amdgcn_mfma_f32_16x16x32_bf16(ahi[r][ks], bhi[c], acc[r][c], 0, 0, 0);
          acc[r][c] = __builtin_amdgcn_mfma_f32_16x16x32_bf16(ahi[r][ks], blo[c], acc[r][c], 0, 0, 0);
          acc[r][c] = __builtin_amdgcn_mfma_f32_16x16x32_bf16(alo[r][ks], bhi[c], acc[r][c], 0, 0, 0);
        }
    }
    // ---- argmin update (top-2 tracking); k ascending => strict < keeps first
#pragma unroll
    for (int c = 0; c < 4; ++c) {
      int kidx = t * 64 + c * 16 + i0;
      float cn = cbn[kidx];
#pragma unroll
      for (int r = 0; r < 4; ++r)
#pragma unroll
        for (int g = 0; g < 4; ++g) {
          float d = fmaf(-2.f, acc[r][c][g], cn);
          bool lt = d < best[r][g];
          float loser = lt ? best[r][g] : d;
          int kl = lt ? bk[r][g] : kidx;
          best[r][g] = lt ? d : best[r][g];
          bk[r][g] = lt ? kidx : bk[r][g];
          bool lt2 = loser < m2[r][g];
          m2[r][g] = lt2 ? loser : m2[r][g];
          k2[r][g] = lt2 ? kl : k2[r][g];
        }
    }
    if (t < 15) {
#pragma unroll
      for (int i = 0; i < 8; ++i)
        *(uint4*)&sB[1 - cur][i * 2048 + tid * 8] = pf[i];
    }
    __syncthreads();
  }

  // ---- cross-lane merge over the 16 col-residue lanes (xor 1,2,4,8) ----
#pragma unroll
  for (int off = 1; off < 16; off <<= 1) {
#pragma unroll
    for (int r = 0; r < 4; ++r)
#pragma unroll
      for (int g = 0; g < 4; ++g) {
        float ob = __shfl_xor(best[r][g], off);
        int obk = __shfl_xor(bk[r][g], off);
        float om2 = __shfl_xor(m2[r][g], off);
        int ok2 = __shfl_xor(k2[r][g], off);
        bool take = (ob < best[r][g]) || (ob == best[r][g] && obk < bk[r][g]);
        float wb = take ? ob : best[r][g];
        int wk = take ? obk : bk[r][g];
        float wm2 = take ? om2 : m2[r][g];
        int wk2 = take ? ok2 : k2[r][g];
        float lb = take ? best[r][g] : ob;
        int lk = take ? bk[r][g] : obk;
        bool t2 = lb < wm2;
        best[r][g] = wb; bk[r][g] = wk;
        m2[r][g] = t2 ? lb : wm2;
        k2[r][g] = t2 ? lk : wk2;
      }
  }

  int* sKK = (int*)&sB[0][0];  // safe to reuse after final barrier of t-loop
  if (i0 == 0) {
#pragma unroll
    for (int r = 0; r < 4; ++r)
#pragma unroll
      for (int g = 0; g < 4; ++g) {
        int fl = (m2[r][g] - best[r][g] < MARGIN) ? 1 : 0;
        sKK[wave * 64 + r * 16 + q * 4 + g] = bk[r][g] | (k2[r][g] << 10) | (fl << 20);
      }
  }
  __syncthreads();

  // ---- epilogue: gather exact fp32 code row, loss, (rare) fp32 rescore ----
  float lacc = 0.f;
#pragma unroll
  for (int r = 0; r < 4; ++r) {
    int kk = sKK[wave * 64 + r * 16 + i0];
    int k1 = kk & 1023, kk2 = (kk >> 10) & 1023, fl = (kk >> 20) & 1;
    size_t tok = (size_t)tok0 + r * 16 + i0;
    float c1a[32], cw[32];
    float s1 = 0.f;
#pragma unroll
    for (int kf = 0; kf < 4; ++kf) {
      float4 u = *(const float4*)&cb[(size_t)k1 * 128 + kf * 32 + q * 8];
      float4 v = *(const float4*)&cb[(size_t)k1 * 128 + kf * 32 + q * 8 + 4];
      c1a[kf * 8 + 0] = u.x; c1a[kf * 8 + 1] = u.y; c1a[kf * 8 + 2] = u.z; c1a[kf * 8 + 3] = u.w;
      c1a[kf * 8 + 4] = v.x; c1a[kf * 8 + 5] = v.y; c1a[kf * 8 + 6] = v.z; c1a[kf * 8 + 7] = v.w;
#pragma unroll
      for (int j = 0; j < 8; ++j) {
        float xv = bf16f((unsigned short)ahi[r][kf][j]) + bf16f((unsigned short)alo[r][kf][j]);
        float df = xv - c1a[kf * 8 + j];
        s1 += df * df;
      }
    }
    s1 += __shfl_xor(s1, 16); s1 += __shfl_xor(s1, 32);
    float s_tok = s1;
#pragma unroll
    for (int j2 = 0; j2 < 32; ++j2) cw[j2] = c1a[j2];

    if (__any(fl)) {  // rare: exact-fp32 rescore of {k1,k2}
      float c2a[32], s1x = 0.f, s2x = 0.f;
#pragma unroll
      for (int kf = 0; kf < 4; ++kf) {
        float4 u2 = *(const float4*)&cb[(size_t)kk2 * 128 + kf * 32 + q * 8];
        float4 v2 = *(const float4*)&cb[(size_t)kk2 * 128 + kf * 32 + q * 8 + 4];
        c2a[kf * 8 + 0] = u2.x; c2a[kf * 8 + 1] = u2.y; c2a[kf * 8 + 2] = u2.z; c2a[kf * 8 + 3] = u2.w;
        c2a[kf * 8 + 4] = v2.x; c2a[kf * 8 + 5] = v2.y; c2a[kf * 8 + 6] = v2.z; c2a[kf * 8 + 7] = v2.w;
        float4 xu = *(const float4*)&xg[tok * 128 + kf * 32 + q * 8];
        float4 xw = *(const float4*)&xg[tok * 128 + kf * 32 + q * 8 + 4];
        float xe[8] = {xu.x, xu.y, xu.z, xu.w, xw.x, xw.y, xw.z, xw.w};
#pragma unroll
        for (int j = 0; j < 8; ++j) {
          float d1 = xe[j] - c1a[kf * 8 + j];
          float d2 = xe[j] - c2a[kf * 8 + j];
          s1x += d1 * d1; s2x += d2 * d2;
        }
      }
      s1x += __shfl_xor(s1x, 16); s1x += __shfl_xor(s1x, 32);
      s2x += __shfl_xor(s2x, 16); s2x += __shfl_xor(s2x, 32);
      bool swap = fl && ((s2x < s1x) || (s2x == s1x && kk2 < k1));
      if (fl) s_tok = swap ? s2x : s1x;
#pragma unroll
      for (int j2 = 0; j2 < 32; ++j2) cw[j2] = swap ? c2a[j2] : cw[j2];
    }
#pragma unroll
    for (int kf = 0; kf < 4; ++kf) {
      *(float4*)&xq[tok * 128 + kf * 32 + q * 8] =
          make_float4(cw[kf * 8 + 0], cw[kf * 8 + 1], cw[kf * 8 + 2], cw[kf * 8 + 3]);
      *(float4*)&xq[tok * 128 + kf * 32 + q * 8 + 4] =
          make_float4(cw[kf * 8 + 4], cw[kf * 8 + 5], cw[kf * 8 + 6], cw[kf * 8 + 7]);
    }
    if (q == 0) lacc += s_tok;
  }
#pragma unroll
  for (int off = 1; off < 64; off <<= 1) lacc += __shfl_xor(lacc, off);
  if (lane == 0) atomicAdd(&loss[tok0 >> 7], lacc * (1.25f / 16384.f));
}

// ---------------------------------------------------------------------------
extern "C" void kernel_launch(void* const* d_in, const int* in_sizes, int n_in,
                              void* d_out, int out_size, void* d_ws, size_t ws_size,
                              hipStream_t stream) {
  const float* x = (const float*)d_in[0];   // [8,64,128,128] fp32
  const float* cb = (const float*)d_in[1];  // [1024,128] fp32
  float* out = (float*)d_out;
  float* xq = out;
  float* loss = out + (size_t)8 * 64 * 128 * 128;  // 512 floats

  // workspace layout (bytes): xhi 16 MB | xlo 16 MB | cbimg 512 KB | cbn 4 KB
  unsigned short* xhi = (unsigned short*)d_ws;
  unsigned short* xlo = xhi + (size_t)65536 * 128;
  unsigned short* cbimg = xlo + (size_t)65536 * 128;
  float* cbn = (float*)(cbimg + (size_t)1024 * 128 * 2);

  hipMemsetAsync(loss, 0, 512 * sizeof(float), stream);
  vq_convert_x<<<4096, 256, 0, stream>>>(x, xhi, xlo);
  vq_convert_cb<<<16, 64, 0, stream>>>(cb, cbimg, cbn);
  vq_main<<<256, 256, 0, stream>>>(xhi, xlo, cbimg, cbn, cb, x, xq, loss);
}